// Round 8
// baseline (237.955 us; speedup 1.0000x reference)
//
#include <hip/hip_runtime.h>
#include <cstdint>
#include <cstddef>

// Problem constants
#define Bb 2
#define Nn 2048
#define DIMM 1024
#define Hh 16
#define DHh 64
#define BH (Bb*Hh)        // 32
#define MROWS (Bb*Nn)     // 4096

typedef __bf16 bf16x8 __attribute__((ext_vector_type(8)));
typedef float f32x4 __attribute__((ext_vector_type(4)));
typedef short s16x4 __attribute__((ext_vector_type(4)));

__device__ __forceinline__ unsigned short f2bf(float f) {
  unsigned u = __float_as_uint(f);
  u += 0x7FFFu + ((u >> 16) & 1u);       // RNE
  return (unsigned short)(u >> 16);
}
__device__ __forceinline__ unsigned short f2bf_fast(float f) {
  return (unsigned short)((__float_as_uint(f) + 0x8000u) >> 16);
}
__device__ __forceinline__ float bf2f(unsigned short s) {
  return __uint_as_float(((unsigned)s) << 16);
}

// async global->LDS, 16B per lane; LDS dest must be wave-uniform base + lane*16
#define GLDS16(g, l) __builtin_amdgcn_global_load_lds( \
    (const __attribute__((address_space(1))) void*)(g), \
    (__attribute__((address_space(3))) void*)(l), 16, 0, 0)

// ---------------------------------------------------------------------------
// Fused prep: grid-partitioned single kernel.
//   [0,4096):       LayerNorm row -> y bf16
//   [4096,7168):    transpose+convert c_attn_w [1024][3072] -> wqkv [3072][1024]
//   [7168,8192):    convert c_proj_w -> wpbf
//   [8192,9216):    convert to_out_w -> wout
//   [9216,9472):    bias_comb bc[n] = sum_c c_proj_b[c] * to_out_w[n][c]
__global__ __launch_bounds__(256) void prep_kernel(
    const float* __restrict__ x, const float* __restrict__ g,
    const float* __restrict__ b,
    const float* __restrict__ c_attn_w, const float* __restrict__ c_proj_w,
    const float* __restrict__ to_out_w, const float* __restrict__ c_proj_b,
    unsigned short* __restrict__ y,
    unsigned short* __restrict__ wqkv, unsigned short* __restrict__ wpbf,
    unsigned short* __restrict__ wout, float* __restrict__ bc) {
  int bid = blockIdx.x;
  int t = threadIdx.x;
  if (bid < 4096) {
    // LayerNorm, one block per row
    int row = bid;
    const float4* xr = (const float4*)(x + (size_t)row * DIMM);
    float4 v = xr[t];
    float s  = v.x + v.y + v.z + v.w;
    float ss = v.x*v.x + v.y*v.y + v.z*v.z + v.w*v.w;
    #pragma unroll
    for (int o = 1; o < 64; o <<= 1) { s += __shfl_xor(s, o); ss += __shfl_xor(ss, o); }
    __shared__ float red[8];
    int wv = t >> 6;
    if ((t & 63) == 0) { red[wv] = s; red[wv + 4] = ss; }
    __syncthreads();
    s  = red[0] + red[1] + red[2] + red[3];
    ss = red[4] + red[5] + red[6] + red[7];
    float mu  = s * (1.0f / DIMM);
    float var = ss * (1.0f / DIMM) - mu * mu;
    float rs  = rsqrtf(var + 1e-5f);
    float4 gv = ((const float4*)g)[t];
    float4 bv = ((const float4*)b)[t];
    ushort4 o4;
    o4.x = f2bf((v.x - mu) * rs * gv.x + bv.x);
    o4.y = f2bf((v.y - mu) * rs * gv.y + bv.y);
    o4.z = f2bf((v.z - mu) * rs * gv.z + bv.z);
    o4.w = f2bf((v.w - mu) * rs * gv.w + bv.w);
    ((ushort4*)y)[(size_t)row * 256 + t] = o4;
  } else if (bid < 7168) {
    // transpose tile 32x32, c_attn_w R=1024, C=3072
    __shared__ float tile[32][33];
    int bb = bid - 4096;
    int bx = bb % 96, by = bb / 96;
    int tx = t & 31, ty = t >> 5;   // 32 x 8
    int x2 = bx * 32 + tx;
    int y0 = by * 32;
    #pragma unroll
    for (int j = 0; j < 32; j += 8)
      tile[ty + j][tx] = c_attn_w[(size_t)(y0 + ty + j) * 3072 + x2];
    __syncthreads();
    int ox  = by * 32 + tx;
    int oy0 = bx * 32;
    #pragma unroll
    for (int j = 0; j < 32; j += 8)
      wqkv[(size_t)(oy0 + ty + j) * 1024 + ox] = f2bf(tile[tx][ty + j]);
  } else if (bid < 9216) {
    bool iswp = bid < 8192;
    int bb = bid - (iswp ? 7168 : 8192);
    const float* in = iswp ? c_proj_w : to_out_w;
    unsigned short* out = iswp ? wpbf : wout;
    int i = (bb * 256 + t) * 4;
    float4 v = *(const float4*)(in + i);
    ushort4 o;
    o.x = f2bf(v.x); o.y = f2bf(v.y); o.z = f2bf(v.z); o.w = f2bf(v.w);
    *(ushort4*)(out + i) = o;
  } else {
    int n = (bid - 9216) * 4 + (t >> 6);
    int lane = t & 63;
    const float4* w = (const float4*)(to_out_w + (size_t)n * DIMM);
    const float4* b4 = (const float4*)c_proj_b;
    float s = 0.0f;
    #pragma unroll
    for (int k = 0; k < 4; k++) {
      float4 wv = w[lane + k * 64], bv = b4[lane + k * 64];
      s += wv.x * bv.x + wv.y * bv.y + wv.z * bv.z + wv.w * bv.w;
    }
    #pragma unroll
    for (int o = 1; o < 64; o <<= 1) s += __shfl_xor(s, o);
    if (lane == 0) bc[n] = s;
  }
}

// ---------------------------------------------------------------------------
// NT GEMM: C[M,N] = A[M,K] * Bt[N,K]^T (+bias). 128x128 tile, BK=64, 4 waves.
// XOR-swizzled LDS (chunk ^= row&7) to kill bank conflicts.
// EPI 0: scatter qkv -> q/k/v [B,H,N,DH] bf16, with fused L2-norm (q*8, k)
// EPI 2: fp32 out [M,N] + bias
// EPI 3: bf16 out [M,N], no bias
template <int EPI>
__global__ __launch_bounds__(256) void gemm_nt(
    const unsigned short* __restrict__ A, const unsigned short* __restrict__ Bt,
    const float* __restrict__ bias,
    unsigned short* __restrict__ obf, float* __restrict__ of32,
    unsigned short* __restrict__ q_std, unsigned short* __restrict__ k_std,
    unsigned short* __restrict__ v_std,
    int M, int N, int K) {
  __shared__ unsigned short sA[128 * 64];
  __shared__ unsigned short sB[128 * 64];
  int t = threadIdx.x;
  int bn = blockIdx.x, bm = blockIdx.y;
  int lane = t & 63, wv = t >> 6;
  int wm = (wv >> 1) * 64, wn = (wv & 1) * 64;
  int l16 = lane & 15, quad = lane >> 4;

  const unsigned short* Ab = A + (size_t)(bm * 128) * K;
  const unsigned short* Bb2 = Bt + (size_t)(bn * 128) * K;
  int srow = t >> 3;                     // 0..31
  int gch = (t & 7) ^ (srow & 7);        // swizzled global chunk for this lane

  f32x4 acc[4][4] = {};

  for (int kt = 0; kt < K; kt += 64) {
    __syncthreads();
    #pragma unroll
    for (int i = 0; i < 4; i++) {
      GLDS16(Ab  + (size_t)(srow + 32 * i) * K + kt + gch * 8, sA + (size_t)(t + 256 * i) * 8);
      GLDS16(Bb2 + (size_t)(srow + 32 * i) * K + kt + gch * 8, sB + (size_t)(t + 256 * i) * 8);
    }
    __syncthreads();
    #pragma unroll
    for (int kk = 0; kk < 2; kk++) {
      int slot = (kk * 4 + quad) ^ (l16 & 7);
      bf16x8 af[4], bfr[4];
      #pragma unroll
      for (int i = 0; i < 4; i++)
        af[i] = *(const bf16x8*)(sA + (size_t)(wm + i * 16 + l16) * 64 + slot * 8);
      #pragma unroll
      for (int j = 0; j < 4; j++)
        bfr[j] = *(const bf16x8*)(sB + (size_t)(wn + j * 16 + l16) * 64 + slot * 8);
      #pragma unroll
      for (int i = 0; i < 4; i++)
        #pragma unroll
        for (int j = 0; j < 4; j++)
          acc[i][j] = __builtin_amdgcn_mfma_f32_16x16x32_bf16(af[i], bfr[j], acc[i][j], 0, 0, 0);
    }
  }

  // epilogue: D row = quad*4+reg, col = l16
  float bvals[4];
  #pragma unroll
  for (int j = 0; j < 4; j++)
    bvals[j] = (EPI == 3) ? 0.0f : bias[bn * 128 + wn + j * 16 + l16];

  if (EPI == 0) {
    int which = bn >> 3;                 // 0=q 1=k 2=v  (bn*128/1024)
    #pragma unroll
    for (int i = 0; i < 4; i++) {
      #pragma unroll
      for (int r = 0; r < 4; r++) {
        int m = bm * 128 + wm + i * 16 + quad * 4 + r;
        float vals[4];
        float ss = 0.0f;
        #pragma unroll
        for (int j = 0; j < 4; j++) {
          vals[j] = acc[i][j][r] + bvals[j];
          ss += vals[j] * vals[j];
        }
        float scale = 1.0f;
        if (which < 2) {
          ss += __shfl_xor(ss, 1); ss += __shfl_xor(ss, 2);
          ss += __shfl_xor(ss, 4); ss += __shfl_xor(ss, 8);
          scale = ((which == 0) ? 8.0f : 1.0f) / fmaxf(sqrtf(ss), 1e-12f);
        }
        int bi = m >> 11, ns = m & 2047;
        unsigned short* dst = (which == 0) ? q_std : ((which == 1) ? k_std : v_std);
        #pragma unroll
        for (int j = 0; j < 4; j++) {
          int n = bn * 128 + wn + j * 16 + l16;
          int nn2 = n & 1023;
          int h = nn2 >> 6, d = nn2 & 63;
          dst[((size_t)((bi * Hh + h) * Nn + ns)) * DHh + d] = f2bf(vals[j] * scale);
        }
      }
    }
  } else {
    #pragma unroll
    for (int i = 0; i < 4; i++) {
      #pragma unroll
      for (int j = 0; j < 4; j++) {
        int n = bn * 128 + wn + j * 16 + l16;
        #pragma unroll
        for (int r = 0; r < 4; r++) {
          int m = bm * 128 + wm + i * 16 + quad * 4 + r;
          float val = acc[i][j][r] + bvals[j];
          if (EPI == 2) of32[(size_t)m * N + n] = val;
          else          obf[(size_t)m * N + n] = f2bf(val);
        }
      }
    }
  }
}

// ---------------------------------------------------------------------------
// Transpose V: [B,H,N,DH] -> [B,H,DH,N] (bf16)
__global__ void transpose_v(const unsigned short* __restrict__ v,
                            unsigned short* __restrict__ vt) {
  __shared__ unsigned short tile[32][33];
  int bh = blockIdx.z;
  const unsigned short* in = v + (size_t)bh * Nn * DHh;
  unsigned short* out = vt + (size_t)bh * DHh * Nn;
  int tx = threadIdx.x, ty = threadIdx.y;
  int x = blockIdx.x * 32 + tx;        // d
  int y0 = blockIdx.y * 32;            // n
  #pragma unroll
  for (int j = 0; j < 32; j += 8)
    tile[ty + j][tx] = in[(size_t)(y0 + ty + j) * DHh + x];
  __syncthreads();
  int ox = blockIdx.y * 32 + tx;       // n
  int oy0 = blockIdx.x * 32;           // d
  #pragma unroll
  for (int j = 0; j < 32; j += 8)
    out[(size_t)(oy0 + ty + j) * Nn + ox] = tile[tx][ty + j];
}

// ---------------------------------------------------------------------------
// Causal cosine-sim attention, register-resident P, split-j, REGISTER-
// PIPELINED staging: tile t+1 is loaded global->VGPR right after the barriers
// of iteration t (overlapping compute of t), then ds_write'd at the top of
// iteration t+1. The vmcnt wait lands after a full compute phase, so the
// barrier drain is cheap (unlike global_load_lds whose vmcnt(0)-at-barrier
// pays full latency per iteration).
// 8 waves (512 thr): waves 0-3 (half 0) j-tiles [0,nh), waves 4-7 [nh,2nh),
// nh = qb+1. Epilogue merges (num, den) of the two halves through LDS.
//   S^T = K·Q^T via mfma(A=K, B=Q);  P^T exp'd in-register = B-operand of
//   16x16x16 MFMA;  O^T[d][m] += V^T[d][j]·P^T[j][m]
// Grid: 512 blocks, paired ordering (heavy+light co-resident).
__global__ __launch_bounds__(512, 4) void attn_kernel(
    const unsigned short* __restrict__ qn, const unsigned short* __restrict__ kn,
    const unsigned short* __restrict__ vt, unsigned short* __restrict__ o_flat) {
  __shared__ char smem[34816];   // 2x(K8KB+V8KB) tiles; merge scratch aliases
  int t = threadIdx.x, lane = t & 63, wv = t >> 6;
  int half = wv >> 2, strip = wv & 3;
  int l16 = lane & 15, quad = lane >> 4;
  int id = blockIdx.x;
  int qb = (id < 256) ? (15 - (id >> 5)) : ((id - 256) >> 5);  // pair heavy+light
  int bh = id & 31;
  int m0 = qb * 128 + strip * 32;               // wave's first q row (seq index)
  const unsigned short* qbase = qn + (size_t)bh * Nn * DHh;
  const unsigned short* kbase = kn + (size_t)bh * Nn * DHh;
  const unsigned short* vbase = vt + (size_t)bh * DHh * Nn;

  unsigned short* myK = (unsigned short*)(smem + half * 16384);
  unsigned short* myV = (unsigned short*)(smem + half * 16384 + 8192);

  // Q fragments (q pre-scaled by 8); same lane layout serves as MFMA B-operand
  bf16x8 aq[2][2];
  #pragma unroll
  for (int i2 = 0; i2 < 2; i2++)
    #pragma unroll
    for (int kk = 0; kk < 2; kk++)
      aq[i2][kk] = *(const bf16x8*)(qbase + (size_t)(m0 + i2 * 16 + l16) * DHh + kk * 32 + quad * 8);

  f32x4 accOT[4][2] = {};       // [dt][i2]: O^T, row=d=quad*4+r, col=m=l16
  float den[2] = {};            // per-lane partial: m = i2*16+l16 (quad-partial)

  int tl = t & 255;                      // thread-in-halfgroup
  int srow = tl >> 3;                    // 0..31
  int gch = (tl & 7) ^ (srow & 7);       // swizzled chunk
  int nh = qb + 1;                       // tiles per half
  int kt0 = half * nh;

  // register staging buffers; preload tile kt=0 of this half
  uint4 rk0, rk1, rv0, rv1;
  {
    int j0 = kt0 * 64;
    rk0 = *(const uint4*)(kbase + (size_t)(j0 + srow)      * DHh + gch * 8);
    rk1 = *(const uint4*)(kbase + (size_t)(j0 + srow + 32) * DHh + gch * 8);
    rv0 = *(const uint4*)(vbase + (size_t)srow        * Nn + j0 + gch * 8);
    rv1 = *(const uint4*)(vbase + (size_t)(srow + 32) * Nn + j0 + gch * 8);
  }

  for (int kt = 0; kt < nh; kt++) {
    int j0 = (kt0 + kt) * 64;
    __syncthreads();                     // all waves done reading previous tile
    *(uint4*)(myK + (size_t)tl * 8)         = rk0;
    *(uint4*)(myK + (size_t)(tl + 256) * 8) = rk1;
    *(uint4*)(myV + (size_t)tl * 8)         = rv0;
    *(uint4*)(myV + (size_t)(tl + 256) * 8) = rv1;
    __syncthreads();                     // writes visible

    if (kt + 1 < nh) {                   // prefetch next tile into regs
      int jn = (kt0 + kt + 1) * 64;
      rk0 = *(const uint4*)(kbase + (size_t)(jn + srow)      * DHh + gch * 8);
      rk1 = *(const uint4*)(kbase + (size_t)(jn + srow + 32) * DHh + gch * 8);
      rv0 = *(const uint4*)(vbase + (size_t)srow        * Nn + jn + gch * 8);
      rv1 = *(const uint4*)(vbase + (size_t)(srow + 32) * Nn + jn + gch * 8);
    }

    if (j0 > m0 + 31) continue;          // fully masked for this wave (uniform)

    // S^T = K·Q^T : sc[jt][i2], row=j_local=quad*4+r, col=m_local=l16
    f32x4 sc[4][2] = {};
    #pragma unroll
    for (int kk = 0; kk < 2; kk++) {
      int slot = (kk * 4 + quad) ^ (l16 & 7);
      #pragma unroll
      for (int jt = 0; jt < 4; jt++) {
        bf16x8 ak = *(const bf16x8*)(myK + (size_t)(jt * 16 + l16) * 64 + slot * 8);
        #pragma unroll
        for (int i2 = 0; i2 < 2; i2++)
          sc[jt][i2] = __builtin_amdgcn_mfma_f32_16x16x32_bf16(ak, aq[i2][kk], sc[jt][i2], 0, 0, 0);
      }
    }

    // exp(s-8) in-register; P^T bf16 is directly the 16x16x16 B-operand
    bool fullTile = (j0 + 63) <= m0;     // wave-uniform
    s16x4 pf[4][2];
    #pragma unroll
    for (int jt = 0; jt < 4; jt++) {
      #pragma unroll
      for (int i2 = 0; i2 < 2; i2++) {
        int m = m0 + i2 * 16 + l16;
        #pragma unroll
        for (int r = 0; r < 4; r++) {
          int j = j0 + jt * 16 + quad * 4 + r;
          float p;
          if (fullTile) p = __expf(sc[jt][i2][r] - 8.0f);
          else          p = (j <= m) ? __expf(sc[jt][i2][r] - 8.0f) : 0.0f;
          den[i2] += p;
          pf[jt][i2][r] = (short)f2bf_fast(p);
        }
      }
    }

    // O^T += V^T · P^T   (A = V^T frag from LDS, 4 bf16/lane: [d=l16][j=quad*4+i])
    #pragma unroll
    for (int jt = 0; jt < 4; jt++) {
      #pragma unroll
      for (int dt = 0; dt < 4; dt++) {
        int row = dt * 16 + l16;
        int ch = (jt * 2 + (quad >> 1)) ^ (l16 & 7);
        s16x4 av = *(const s16x4*)(myV + (size_t)row * 64 + ch * 8 + (quad & 1) * 4);
        #pragma unroll
        for (int i2 = 0; i2 < 2; i2++)
          accOT[dt][i2] = __builtin_amdgcn_mfma_f32_16x16x16bf16_1k(av, pf[jt][i2], accOT[dt][i2], 0, 0, 0);
      }
    }
  }

  // intra-wave den reduction across quads (j-direction lives on lane>>4)
  #pragma unroll
  for (int i2 = 0; i2 < 2; i2++) {
    float d = den[i2];
    d += __shfl_xor(d, 16); d += __shfl_xor(d, 32);
    den[i2] = d;
  }

  // merge halves through LDS (reuse tile buffers; all loop reads done)
  float* smemf = (float*)smem;
  __syncthreads();
  float* scr = smemf + strip * 2176;     // 2048 acc + 128 den per strip
  if (half == 1) {
    #pragma unroll
    for (int dt = 0; dt < 4; dt++)
      #pragma unroll
      for (int i2 = 0; i2 < 2; i2++)
        *(f32x4*)(scr + ((size_t)(dt * 2 + i2) * 64 + lane) * 4) = accOT[dt][i2];
    scr[2048 + lane] = den[0];
    scr[2048 + 64 + lane] = den[1];
  }
  __syncthreads();
  if (half == 0) {
    float dinv[2];
    dinv[0] = 1.0f / (den[0] + scr[2048 + lane]);
    dinv[1] = 1.0f / (den[1] + scr[2048 + 64 + lane]);
    int bi = bh >> 4, h = bh & 15;
    #pragma unroll
    for (int i2 = 0; i2 < 2; i2++) {
      #pragma unroll
      for (int dt = 0; dt < 4; dt++) {
        f32x4 o = accOT[dt][i2] + *(const f32x4*)(scr + ((size_t)(dt * 2 + i2) * 64 + lane) * 4);
        ushort4 o4;
        o4.x = f2bf(o[0] * dinv[i2]);
        o4.y = f2bf(o[1] * dinv[i2]);
        o4.z = f2bf(o[2] * dinv[i2]);
        o4.w = f2bf(o[3] * dinv[i2]);
        int ns = m0 + i2 * 16 + l16;
        int d0 = dt * 16 + quad * 4;
        *(ushort4*)(o_flat + ((size_t)(bi * Nn + ns)) * DIMM + h * DHh + d0) = o4;
      }
    }
  }
}

// ---------------------------------------------------------------------------
extern "C" void kernel_launch(void* const* d_in, const int* in_sizes, int n_in,
                              void* d_out, int out_size, void* d_ws, size_t ws_size,
                              hipStream_t stream) {
  const float* x        = (const float*)d_in[0];
  const float* g        = (const float*)d_in[1];
  const float* b        = (const float*)d_in[2];
  const float* c_attn_w = (const float*)d_in[3];
  const float* c_attn_b = (const float*)d_in[4];
  const float* c_proj_w = (const float*)d_in[5];
  const float* c_proj_b = (const float*)d_in[6];
  const float* to_out_w = (const float*)d_in[7];
  float* out = (float*)d_out;

  char* p = (char*)d_ws;
  unsigned short* y     = (unsigned short*)(p + ((size_t)0  << 20)); // 8 MB (also o_flat)
  unsigned short* qbuf  = (unsigned short*)(p + ((size_t)8  << 20)); // 8 MB
  unsigned short* kbuf  = (unsigned short*)(p + ((size_t)16 << 20)); // 8 MB
  unsigned short* vbuf  = (unsigned short*)(p + ((size_t)24 << 20)); // 8 MB
  unsigned short* vtb   = (unsigned short*)(p + ((size_t)32 << 20)); // 8 MB (after wpbf/wout dead)
  unsigned short* wpbf  = (unsigned short*)(p + ((size_t)32 << 20)); // 2 MB (dead before vtb)
  unsigned short* wout  = (unsigned short*)(p + ((size_t)34 << 20)); // 2 MB (dead before vtb)
  unsigned short* wqkv  = (unsigned short*)(p + ((size_t)40 << 20)); // 6 MB
  unsigned short* wcomb = (unsigned short*)(p + ((size_t)46 << 20)); // 2 MB
  float*          bc    = (float*)        (p + ((size_t)48 << 20)); // 4 KB

  // 1. fused prep: LayerNorm -> y, transpose c_attn_w, convert wp/wout, bias
  prep_kernel<<<9472, 256, 0, stream>>>(x, g, b, c_attn_w, c_proj_w, to_out_w,
                                        c_proj_b, y, wqkv, wpbf, wout, bc);
  // 2. combined weight: wcomb[n][j] = sum_c Wo[n][c] * Wp[j][c]
  gemm_nt<3><<<dim3(DIMM / 128, DIMM / 128), 256, 0, stream>>>(
      wout, wpbf, nullptr, wcomb, nullptr, nullptr, nullptr, nullptr, DIMM, DIMM, DIMM);
  // 3. qkv GEMM + scatter + fused l2norm (q*8, k)
  gemm_nt<0><<<dim3(3 * DIMM / 128, MROWS / 128), 256, 0, stream>>>(
      y, wqkv, c_attn_b, nullptr, nullptr, qbuf, kbuf, vbuf, MROWS, 3 * DIMM, DIMM);
  // 4. V transpose (overwrites wpbf/wout region — both dead now)
  transpose_v<<<dim3(DHh / 32, Nn / 32, BH), dim3(32, 8), 0, stream>>>(vbuf, vtb);
  // 5. attention -> o_flat (reuses y)
  attn_kernel<<<512, 512, 0, stream>>>(qbuf, kbuf, vtb, y);
  // 6. fused (c_proj ∘ to_out): out = o_flat @ wcomb^T + bc  (fp32)
  gemm_nt<2><<<dim3(DIMM / 128, MROWS / 128), 256, 0, stream>>>(
      y, wcomb, bc, nullptr, out, nullptr, nullptr, nullptr, MROWS, DIMM, DIMM);
}

// Round 9
// 216.253 us; speedup vs baseline: 1.1004x; 1.1004x over previous
//
#include <hip/hip_runtime.h>
#include <cstdint>
#include <cstddef>

// Problem constants
#define Bb 2
#define Nn 2048
#define DIMM 1024
#define Hh 16
#define DHh 64
#define BH (Bb*Hh)        // 32
#define MROWS (Bb*Nn)     // 4096

typedef __bf16 bf16x8 __attribute__((ext_vector_type(8)));
typedef float f32x4 __attribute__((ext_vector_type(4)));
typedef short s16x4 __attribute__((ext_vector_type(4)));

__device__ __forceinline__ unsigned short f2bf(float f) {
  unsigned u = __float_as_uint(f);
  u += 0x7FFFu + ((u >> 16) & 1u);       // RNE
  return (unsigned short)(u >> 16);
}
__device__ __forceinline__ unsigned short f2bf_fast(float f) {
  return (unsigned short)((__float_as_uint(f) + 0x8000u) >> 16);
}
__device__ __forceinline__ float bf2f(unsigned short s) {
  return __uint_as_float(((unsigned)s) << 16);
}

// async global->LDS, 16B per lane; LDS dest must be wave-uniform base + lane*16
#define GLDS16(g, l) __builtin_amdgcn_global_load_lds( \
    (const __attribute__((address_space(1))) void*)(g), \
    (__attribute__((address_space(3))) void*)(l), 16, 0, 0)

// ---------------------------------------------------------------------------
// Fused prep: grid-partitioned single kernel.
//   [0,4096):       LayerNorm row -> y bf16
//   [4096,7168):    transpose+convert c_attn_w [1024][3072] -> wqkv [3072][1024]
//   [7168,8192):    convert c_proj_w -> wpbf
//   [8192,9216):    convert to_out_w -> wout
//   [9216,9472):    bias_comb bc[n] = sum_c c_proj_b[c] * to_out_w[n][c]
__global__ __launch_bounds__(256) void prep_kernel(
    const float* __restrict__ x, const float* __restrict__ g,
    const float* __restrict__ b,
    const float* __restrict__ c_attn_w, const float* __restrict__ c_proj_w,
    const float* __restrict__ to_out_w, const float* __restrict__ c_proj_b,
    unsigned short* __restrict__ y,
    unsigned short* __restrict__ wqkv, unsigned short* __restrict__ wpbf,
    unsigned short* __restrict__ wout, float* __restrict__ bc) {
  int bid = blockIdx.x;
  int t = threadIdx.x;
  if (bid < 4096) {
    // LayerNorm, one block per row
    int row = bid;
    const float4* xr = (const float4*)(x + (size_t)row * DIMM);
    float4 v = xr[t];
    float s  = v.x + v.y + v.z + v.w;
    float ss = v.x*v.x + v.y*v.y + v.z*v.z + v.w*v.w;
    #pragma unroll
    for (int o = 1; o < 64; o <<= 1) { s += __shfl_xor(s, o); ss += __shfl_xor(ss, o); }
    __shared__ float red[8];
    int wv = t >> 6;
    if ((t & 63) == 0) { red[wv] = s; red[wv + 4] = ss; }
    __syncthreads();
    s  = red[0] + red[1] + red[2] + red[3];
    ss = red[4] + red[5] + red[6] + red[7];
    float mu  = s * (1.0f / DIMM);
    float var = ss * (1.0f / DIMM) - mu * mu;
    float rs  = rsqrtf(var + 1e-5f);
    float4 gv = ((const float4*)g)[t];
    float4 bv = ((const float4*)b)[t];
    ushort4 o4;
    o4.x = f2bf((v.x - mu) * rs * gv.x + bv.x);
    o4.y = f2bf((v.y - mu) * rs * gv.y + bv.y);
    o4.z = f2bf((v.z - mu) * rs * gv.z + bv.z);
    o4.w = f2bf((v.w - mu) * rs * gv.w + bv.w);
    ((ushort4*)y)[(size_t)row * 256 + t] = o4;
  } else if (bid < 7168) {
    // transpose tile 32x32, c_attn_w R=1024, C=3072
    __shared__ float tile[32][33];
    int bb = bid - 4096;
    int bx = bb % 96, by = bb / 96;
    int tx = t & 31, ty = t >> 5;   // 32 x 8
    int x2 = bx * 32 + tx;
    int y0 = by * 32;
    #pragma unroll
    for (int j = 0; j < 32; j += 8)
      tile[ty + j][tx] = c_attn_w[(size_t)(y0 + ty + j) * 3072 + x2];
    __syncthreads();
    int ox  = by * 32 + tx;
    int oy0 = bx * 32;
    #pragma unroll
    for (int j = 0; j < 32; j += 8)
      wqkv[(size_t)(oy0 + ty + j) * 1024 + ox] = f2bf(tile[tx][ty + j]);
  } else if (bid < 9216) {
    bool iswp = bid < 8192;
    int bb = bid - (iswp ? 7168 : 8192);
    const float* in = iswp ? c_proj_w : to_out_w;
    unsigned short* out = iswp ? wpbf : wout;
    int i = (bb * 256 + t) * 4;
    float4 v = *(const float4*)(in + i);
    ushort4 o;
    o.x = f2bf(v.x); o.y = f2bf(v.y); o.z = f2bf(v.z); o.w = f2bf(v.w);
    *(ushort4*)(out + i) = o;
  } else {
    int n = (bid - 9216) * 4 + (t >> 6);
    int lane = t & 63;
    const float4* w = (const float4*)(to_out_w + (size_t)n * DIMM);
    const float4* b4 = (const float4*)c_proj_b;
    float s = 0.0f;
    #pragma unroll
    for (int k = 0; k < 4; k++) {
      float4 wv = w[lane + k * 64], bv = b4[lane + k * 64];
      s += wv.x * bv.x + wv.y * bv.y + wv.z * bv.z + wv.w * bv.w;
    }
    #pragma unroll
    for (int o = 1; o < 64; o <<= 1) s += __shfl_xor(s, o);
    if (lane == 0) bc[n] = s;
  }
}

// ---------------------------------------------------------------------------
// NT GEMM body: C[M,N] = A[M,K] * Bt[N,K]^T (+bias). 128x128 tile, BK=64,
// 4 waves. XOR-swizzled LDS (chunk ^= row&7) to kill bank conflicts.
// EPI 0: scatter qkv -> q/k/v [B,H,N,DH] bf16, with fused L2-norm (q*8, k)
// EPI 2: fp32 out [M,N] + bias
// EPI 3: bf16 out [M,N], no bias
template <int EPI>
__device__ __forceinline__ void gemm_body(
    const unsigned short* __restrict__ A, const unsigned short* __restrict__ Bt,
    const float* __restrict__ bias,
    unsigned short* __restrict__ obf, float* __restrict__ of32,
    unsigned short* __restrict__ q_std, unsigned short* __restrict__ k_std,
    unsigned short* __restrict__ v_std,
    int M, int N, int K, int bn, int bm,
    unsigned short* sA, unsigned short* sB) {
  int t = threadIdx.x;
  int lane = t & 63, wv = t >> 6;
  int wm = (wv >> 1) * 64, wn = (wv & 1) * 64;
  int l16 = lane & 15, quad = lane >> 4;

  const unsigned short* Ab = A + (size_t)(bm * 128) * K;
  const unsigned short* Bb2 = Bt + (size_t)(bn * 128) * K;
  int srow = t >> 3;                     // 0..31
  int gch = (t & 7) ^ (srow & 7);        // swizzled global chunk for this lane

  f32x4 acc[4][4] = {};

  for (int kt = 0; kt < K; kt += 64) {
    __syncthreads();
    #pragma unroll
    for (int i = 0; i < 4; i++) {
      GLDS16(Ab  + (size_t)(srow + 32 * i) * K + kt + gch * 8, sA + (size_t)(t + 256 * i) * 8);
      GLDS16(Bb2 + (size_t)(srow + 32 * i) * K + kt + gch * 8, sB + (size_t)(t + 256 * i) * 8);
    }
    __syncthreads();
    #pragma unroll
    for (int kk = 0; kk < 2; kk++) {
      int slot = (kk * 4 + quad) ^ (l16 & 7);
      bf16x8 af[4], bfr[4];
      #pragma unroll
      for (int i = 0; i < 4; i++)
        af[i] = *(const bf16x8*)(sA + (size_t)(wm + i * 16 + l16) * 64 + slot * 8);
      #pragma unroll
      for (int j = 0; j < 4; j++)
        bfr[j] = *(const bf16x8*)(sB + (size_t)(wn + j * 16 + l16) * 64 + slot * 8);
      #pragma unroll
      for (int i = 0; i < 4; i++)
        #pragma unroll
        for (int j = 0; j < 4; j++)
          acc[i][j] = __builtin_amdgcn_mfma_f32_16x16x32_bf16(af[i], bfr[j], acc[i][j], 0, 0, 0);
    }
  }

  // epilogue: D row = quad*4+reg, col = l16
  float bvals[4];
  #pragma unroll
  for (int j = 0; j < 4; j++)
    bvals[j] = (EPI == 3) ? 0.0f : bias[bn * 128 + wn + j * 16 + l16];

  if (EPI == 0) {
    int which = bn >> 3;                 // 0=q 1=k 2=v  (bn*128/1024)
    #pragma unroll
    for (int i = 0; i < 4; i++) {
      #pragma unroll
      for (int r = 0; r < 4; r++) {
        int m = bm * 128 + wm + i * 16 + quad * 4 + r;
        float vals[4];
        float ss = 0.0f;
        #pragma unroll
        for (int j = 0; j < 4; j++) {
          vals[j] = acc[i][j][r] + bvals[j];
          ss += vals[j] * vals[j];
        }
        float scale = 1.0f;
        if (which < 2) {
          ss += __shfl_xor(ss, 1); ss += __shfl_xor(ss, 2);
          ss += __shfl_xor(ss, 4); ss += __shfl_xor(ss, 8);
          scale = ((which == 0) ? 8.0f : 1.0f) / fmaxf(sqrtf(ss), 1e-12f);
        }
        int bi = m >> 11, ns = m & 2047;
        unsigned short* dst = (which == 0) ? q_std : ((which == 1) ? k_std : v_std);
        #pragma unroll
        for (int j = 0; j < 4; j++) {
          int n = bn * 128 + wn + j * 16 + l16;
          int nn2 = n & 1023;
          int h = nn2 >> 6, d = nn2 & 63;
          dst[((size_t)((bi * Hh + h) * Nn + ns)) * DHh + d] = f2bf(vals[j] * scale);
        }
      }
    }
  } else {
    #pragma unroll
    for (int i = 0; i < 4; i++) {
      #pragma unroll
      for (int j = 0; j < 4; j++) {
        int n = bn * 128 + wn + j * 16 + l16;
        #pragma unroll
        for (int r = 0; r < 4; r++) {
          int m = bm * 128 + wm + i * 16 + quad * 4 + r;
          float val = acc[i][j][r] + bvals[j];
          if (EPI == 2) of32[(size_t)m * N + n] = val;
          else          obf[(size_t)m * N + n] = f2bf(val);
        }
      }
    }
  }
}

// Fused launch: qkv GEMM (bn<24, grid 24x32) + wcomb GEMM (bn in {24,25},
// remapped to the 8x8 tile grid of wcomb[n][j] = sum_c Wo[n][c]*Wp[j][c]).
// Both depend only on prep outputs; 64 rider blocks hide inside the 768-block
// qkv dispatch instead of a serialized 25%-occupancy launch.
__global__ __launch_bounds__(256) void gemm_qkv_wcomb(
    const unsigned short* __restrict__ y, const unsigned short* __restrict__ wqkv,
    const float* __restrict__ c_attn_b,
    unsigned short* __restrict__ q_std, unsigned short* __restrict__ k_std,
    unsigned short* __restrict__ v_std,
    const unsigned short* __restrict__ wout, const unsigned short* __restrict__ wpbf,
    unsigned short* __restrict__ wcomb) {
  __shared__ unsigned short sA[128 * 64];
  __shared__ unsigned short sB[128 * 64];
  int bn = blockIdx.x, bm = blockIdx.y;
  if (bn < 24) {
    gemm_body<0>(y, wqkv, c_attn_b, nullptr, nullptr, q_std, k_std, v_std,
                 MROWS, 3 * DIMM, DIMM, bn, bm, sA, sB);
  } else {
    int idx = (bn - 24) * 32 + bm;       // 0..63
    gemm_body<3>(wout, wpbf, nullptr, wcomb, nullptr, nullptr, nullptr, nullptr,
                 DIMM, DIMM, DIMM, idx & 7, idx >> 3, sA, sB);
  }
}

// Standalone final GEMM (fp32 out + bias)
__global__ __launch_bounds__(256) void gemm_final(
    const unsigned short* __restrict__ A, const unsigned short* __restrict__ Bt,
    const float* __restrict__ bias, float* __restrict__ of32) {
  __shared__ unsigned short sA[128 * 64];
  __shared__ unsigned short sB[128 * 64];
  gemm_body<2>(A, Bt, bias, nullptr, of32, nullptr, nullptr, nullptr,
               MROWS, DIMM, DIMM, blockIdx.x, blockIdx.y, sA, sB);
}

// ---------------------------------------------------------------------------
// Transpose V: [B,H,N,DH] -> [B,H,DH,N] (bf16)
__global__ void transpose_v(const unsigned short* __restrict__ v,
                            unsigned short* __restrict__ vt) {
  __shared__ unsigned short tile[32][33];
  int bh = blockIdx.z;
  const unsigned short* in = v + (size_t)bh * Nn * DHh;
  unsigned short* out = vt + (size_t)bh * DHh * Nn;
  int tx = threadIdx.x, ty = threadIdx.y;
  int x = blockIdx.x * 32 + tx;        // d
  int y0 = blockIdx.y * 32;            // n
  #pragma unroll
  for (int j = 0; j < 32; j += 8)
    tile[ty + j][tx] = in[(size_t)(y0 + ty + j) * DHh + x];
  __syncthreads();
  int ox = blockIdx.y * 32 + tx;       // n
  int oy0 = blockIdx.x * 32;           // d
  #pragma unroll
  for (int j = 0; j < 32; j += 8)
    out[(size_t)(oy0 + ty + j) * Nn + ox] = tile[tx][ty + j];
}

// ---------------------------------------------------------------------------
// Causal cosine-sim attention (R5 structure — best measured), register-
// resident P, split-j within the block: 8 waves (512 thr). Waves 0-3 (half 0)
// process j-tiles [0, nh); waves 4-7 (half 1) process [nh, 2nh), nh = qb+1.
// Equal trip counts -> uniform barriers, halved serial critical path. Each
// half stages K/V into its own LDS buffer via global_load_lds. Epilogue
// merges (num, den) of the two halves through LDS.
//   S^T = K·Q^T via mfma(A=K, B=Q);  P^T exp'd in-register = B-operand of
//   16x16x16 MFMA;  O^T[d][m] += V^T[d][j]·P^T[j][m]
// NOTE (R7 lesson): do NOT add cross-iteration register prefetch here — at
// __launch_bounds__(512,4) the VGPR budget has no headroom and the staging
// registers spill to scratch (HBM), costing ~10 µs (WRITE_SIZE 10->22 MB).
// Grid: 512 blocks, paired ordering (heavy+light co-resident).
__global__ __launch_bounds__(512, 4) void attn_kernel(
    const unsigned short* __restrict__ qn, const unsigned short* __restrict__ kn,
    const unsigned short* __restrict__ vt, unsigned short* __restrict__ o_flat) {
  __shared__ float smemf[8704];   // 34816 B: 2x(K8KB+V8KB) tiles / merge scratch
  int t = threadIdx.x, lane = t & 63, wv = t >> 6;
  int half = wv >> 2, strip = wv & 3;
  int l16 = lane & 15, quad = lane >> 4;
  int id = blockIdx.x;
  int qb = (id < 256) ? (15 - (id >> 5)) : ((id - 256) >> 5);  // pair heavy+light
  int bh = id & 31;
  int m0 = qb * 128 + strip * 32;               // wave's first q row (seq index)
  const unsigned short* qbase = qn + (size_t)bh * Nn * DHh;
  const unsigned short* kbase = kn + (size_t)bh * Nn * DHh;
  const unsigned short* vbase = vt + (size_t)bh * DHh * Nn;

  unsigned short* myK = (unsigned short*)((char*)smemf + half * 16384);
  unsigned short* myV = (unsigned short*)((char*)smemf + half * 16384 + 8192);

  // Q fragments (q pre-scaled by 8); same lane layout serves as MFMA B-operand
  bf16x8 aq[2][2];
  #pragma unroll
  for (int i2 = 0; i2 < 2; i2++)
    #pragma unroll
    for (int kk = 0; kk < 2; kk++)
      aq[i2][kk] = *(const bf16x8*)(qbase + (size_t)(m0 + i2 * 16 + l16) * DHh + kk * 32 + quad * 8);

  f32x4 accOT[4][2] = {};       // [dt][i2]: O^T, row=d=quad*4+r, col=m=l16
  float den[2] = {};            // per-lane partial: m = i2*16+l16 (quad-partial)

  int tl = t & 255;                      // thread-in-halfgroup
  int srow = tl >> 3;                    // 0..31
  int gch = (tl & 7) ^ (srow & 7);       // swizzled chunk
  int nh = qb + 1;                       // tiles per half
  int kt0 = half * nh;

  for (int kt = 0; kt < nh; kt++) {
    int j0 = (kt0 + kt) * 64;
    __syncthreads();
    GLDS16(kbase + (size_t)(j0 + srow)      * DHh + gch * 8, myK + (size_t)tl * 8);
    GLDS16(kbase + (size_t)(j0 + srow + 32) * DHh + gch * 8, myK + (size_t)(tl + 256) * 8);
    GLDS16(vbase + (size_t)srow        * Nn + j0 + gch * 8, myV + (size_t)tl * 8);
    GLDS16(vbase + (size_t)(srow + 32) * Nn + j0 + gch * 8, myV + (size_t)(tl + 256) * 8);
    __syncthreads();

    if (j0 > m0 + 31) continue;          // fully masked for this wave (uniform)

    // S^T = K·Q^T : sc[jt][i2], row=j_local=quad*4+r, col=m_local=l16
    f32x4 sc[4][2] = {};
    #pragma unroll
    for (int kk = 0; kk < 2; kk++) {
      int slot = (kk * 4 + quad) ^ (l16 & 7);
      #pragma unroll
      for (int jt = 0; jt < 4; jt++) {
        bf16x8 ak = *(const bf16x8*)(myK + (size_t)(jt * 16 + l16) * 64 + slot * 8);
        #pragma unroll
        for (int i2 = 0; i2 < 2; i2++)
          sc[jt][i2] = __builtin_amdgcn_mfma_f32_16x16x32_bf16(ak, aq[i2][kk], sc[jt][i2], 0, 0, 0);
      }
    }

    // exp(s-8) in-register; P^T bf16 is directly the 16x16x16 B-operand
    bool fullTile = (j0 + 63) <= m0;     // wave-uniform
    s16x4 pf[4][2];
    #pragma unroll
    for (int jt = 0; jt < 4; jt++) {
      #pragma unroll
      for (int i2 = 0; i2 < 2; i2++) {
        int m = m0 + i2 * 16 + l16;
        #pragma unroll
        for (int r = 0; r < 4; r++) {
          int j = j0 + jt * 16 + quad * 4 + r;
          float p;
          if (fullTile) p = __expf(sc[jt][i2][r] - 8.0f);
          else          p = (j <= m) ? __expf(sc[jt][i2][r] - 8.0f) : 0.0f;
          den[i2] += p;
          pf[jt][i2][r] = (short)f2bf_fast(p);
        }
      }
    }

    // O^T += V^T · P^T   (A = V^T frag from LDS, 4 bf16/lane: [d=l16][j=quad*4+i])
    #pragma unroll
    for (int jt = 0; jt < 4; jt++) {
      #pragma unroll
      for (int dt = 0; dt < 4; dt++) {
        int row = dt * 16 + l16;
        int ch = (jt * 2 + (quad >> 1)) ^ (l16 & 7);
        s16x4 av = *(const s16x4*)(myV + (size_t)row * 64 + ch * 8 + (quad & 1) * 4);
        #pragma unroll
        for (int i2 = 0; i2 < 2; i2++)
          accOT[dt][i2] = __builtin_amdgcn_mfma_f32_16x16x16bf16_1k(av, pf[jt][i2], accOT[dt][i2], 0, 0, 0);
      }
    }
  }

  // intra-wave den reduction across quads (j-direction lives on lane>>4)
  #pragma unroll
  for (int i2 = 0; i2 < 2; i2++) {
    float d = den[i2];
    d += __shfl_xor(d, 16); d += __shfl_xor(d, 32);
    den[i2] = d;
  }

  // merge halves through LDS (reuse tile buffers; all loop reads done)
  __syncthreads();
  float* scr = smemf + strip * 2176;     // 2048 acc + 128 den per strip
  if (half == 1) {
    #pragma unroll
    for (int dt = 0; dt < 4; dt++)
      #pragma unroll
      for (int i2 = 0; i2 < 2; i2++)
        *(f32x4*)(scr + ((size_t)(dt * 2 + i2) * 64 + lane) * 4) = accOT[dt][i2];
    scr[2048 + lane] = den[0];
    scr[2048 + 64 + lane] = den[1];
  }
  __syncthreads();
  if (half == 0) {
    float dinv[2];
    dinv[0] = 1.0f / (den[0] + scr[2048 + lane]);
    dinv[1] = 1.0f / (den[1] + scr[2048 + 64 + lane]);
    int bi = bh >> 4, h = bh & 15;
    #pragma unroll
    for (int i2 = 0; i2 < 2; i2++) {
      #pragma unroll
      for (int dt = 0; dt < 4; dt++) {
        f32x4 o = accOT[dt][i2] + *(const f32x4*)(scr + ((size_t)(dt * 2 + i2) * 64 + lane) * 4);
        ushort4 o4;
        o4.x = f2bf(o[0] * dinv[i2]);
        o4.y = f2bf(o[1] * dinv[i2]);
        o4.z = f2bf(o[2] * dinv[i2]);
        o4.w = f2bf(o[3] * dinv[i2]);
        int ns = m0 + i2 * 16 + l16;
        int d0 = dt * 16 + quad * 4;
        *(ushort4*)(o_flat + ((size_t)(bi * Nn + ns)) * DIMM + h * DHh + d0) = o4;
      }
    }
  }
}

// ---------------------------------------------------------------------------
extern "C" void kernel_launch(void* const* d_in, const int* in_sizes, int n_in,
                              void* d_out, int out_size, void* d_ws, size_t ws_size,
                              hipStream_t stream) {
  const float* x        = (const float*)d_in[0];
  const float* g        = (const float*)d_in[1];
  const float* b        = (const float*)d_in[2];
  const float* c_attn_w = (const float*)d_in[3];
  const float* c_attn_b = (const float*)d_in[4];
  const float* c_proj_w = (const float*)d_in[5];
  const float* c_proj_b = (const float*)d_in[6];
  const float* to_out_w = (const float*)d_in[7];
  float* out = (float*)d_out;

  char* p = (char*)d_ws;
  unsigned short* y     = (unsigned short*)(p + ((size_t)0  << 20)); // 8 MB (also o_flat)
  unsigned short* qbuf  = (unsigned short*)(p + ((size_t)8  << 20)); // 8 MB
  unsigned short* kbuf  = (unsigned short*)(p + ((size_t)16 << 20)); // 8 MB
  unsigned short* vbuf  = (unsigned short*)(p + ((size_t)24 << 20)); // 8 MB
  unsigned short* vtb   = (unsigned short*)(p + ((size_t)32 << 20)); // 8 MB (after wpbf/wout dead)
  unsigned short* wpbf  = (unsigned short*)(p + ((size_t)32 << 20)); // 2 MB (dead before vtb)
  unsigned short* wout  = (unsigned short*)(p + ((size_t)34 << 20)); // 2 MB (dead before vtb)
  unsigned short* wqkv  = (unsigned short*)(p + ((size_t)40 << 20)); // 6 MB
  unsigned short* wcomb = (unsigned short*)(p + ((size_t)46 << 20)); // 2 MB
  float*          bc    = (float*)        (p + ((size_t)48 << 20)); // 4 KB

  // 1. fused prep: LayerNorm -> y, transpose c_attn_w, convert wp/wout, bias
  prep_kernel<<<9472, 256, 0, stream>>>(x, g, b, c_attn_w, c_proj_w, to_out_w,
                                        c_proj_b, y, wqkv, wpbf, wout, bc);
  // 2. qkv GEMM + scatter + fused l2norm, with wcomb GEMM riding along
  gemm_qkv_wcomb<<<dim3(26, MROWS / 128), 256, 0, stream>>>(
      y, wqkv, c_attn_b, qbuf, kbuf, vbuf, wout, wpbf, wcomb);
  // 3. V transpose (overwrites wpbf/wout region — both dead now)
  transpose_v<<<dim3(DHh / 32, Nn / 32, BH), dim3(32, 8), 0, stream>>>(vbuf, vtb);
  // 4. attention -> o_flat (reuses y)
  attn_kernel<<<512, 512, 0, stream>>>(qbuf, kbuf, vtb, y);
  // 5. fused (c_proj ∘ to_out): out = o_flat @ wcomb^T + bc  (fp32)
  gemm_final<<<dim3(DIMM / 128, MROWS / 128), 256, 0, stream>>>(y, wcomb, bc, out);
}

// Round 10
// 208.397 us; speedup vs baseline: 1.1418x; 1.0377x over previous
//
#include <hip/hip_runtime.h>
#include <cstdint>
#include <cstddef>

// Problem constants
#define Bb 2
#define Nn 2048
#define DIMM 1024
#define Hh 16
#define DHh 64
#define BH (Bb*Hh)        // 32
#define MROWS (Bb*Nn)     // 4096

typedef __bf16 bf16x8 __attribute__((ext_vector_type(8)));
typedef float f32x4 __attribute__((ext_vector_type(4)));
typedef short s16x4 __attribute__((ext_vector_type(4)));

__device__ __forceinline__ unsigned short f2bf(float f) {
  unsigned u = __float_as_uint(f);
  u += 0x7FFFu + ((u >> 16) & 1u);       // RNE
  return (unsigned short)(u >> 16);
}
__device__ __forceinline__ unsigned short f2bf_fast(float f) {
  return (unsigned short)((__float_as_uint(f) + 0x8000u) >> 16);
}
__device__ __forceinline__ float bf2f(unsigned short s) {
  return __uint_as_float(((unsigned)s) << 16);
}

// async global->LDS, 16B per lane; LDS dest must be wave-uniform base + lane*16
#define GLDS16(g, l) __builtin_amdgcn_global_load_lds( \
    (const __attribute__((address_space(1))) void*)(g), \
    (__attribute__((address_space(3))) void*)(l), 16, 0, 0)

// ---------------------------------------------------------------------------
// Fused prep: grid-partitioned single kernel.
//   [0,4096):       LayerNorm row -> y bf16
//   [4096,7168):    transpose+convert c_attn_w [1024][3072] -> wqkv [3072][1024]
//   [7168,8192):    convert c_proj_w -> wpbf
//   [8192,9216):    convert to_out_w -> wout
//   [9216,9472):    bias_comb bc[n] = sum_c c_proj_b[c] * to_out_w[n][c]
__global__ __launch_bounds__(256) void prep_kernel(
    const float* __restrict__ x, const float* __restrict__ g,
    const float* __restrict__ b,
    const float* __restrict__ c_attn_w, const float* __restrict__ c_proj_w,
    const float* __restrict__ to_out_w, const float* __restrict__ c_proj_b,
    unsigned short* __restrict__ y,
    unsigned short* __restrict__ wqkv, unsigned short* __restrict__ wpbf,
    unsigned short* __restrict__ wout, float* __restrict__ bc) {
  int bid = blockIdx.x;
  int t = threadIdx.x;
  if (bid < 4096) {
    // LayerNorm, one block per row
    int row = bid;
    const float4* xr = (const float4*)(x + (size_t)row * DIMM);
    float4 v = xr[t];
    float s  = v.x + v.y + v.z + v.w;
    float ss = v.x*v.x + v.y*v.y + v.z*v.z + v.w*v.w;
    #pragma unroll
    for (int o = 1; o < 64; o <<= 1) { s += __shfl_xor(s, o); ss += __shfl_xor(ss, o); }
    __shared__ float red[8];
    int wv = t >> 6;
    if ((t & 63) == 0) { red[wv] = s; red[wv + 4] = ss; }
    __syncthreads();
    s  = red[0] + red[1] + red[2] + red[3];
    ss = red[4] + red[5] + red[6] + red[7];
    float mu  = s * (1.0f / DIMM);
    float var = ss * (1.0f / DIMM) - mu * mu;
    float rs  = rsqrtf(var + 1e-5f);
    float4 gv = ((const float4*)g)[t];
    float4 bv = ((const float4*)b)[t];
    ushort4 o4;
    o4.x = f2bf((v.x - mu) * rs * gv.x + bv.x);
    o4.y = f2bf((v.y - mu) * rs * gv.y + bv.y);
    o4.z = f2bf((v.z - mu) * rs * gv.z + bv.z);
    o4.w = f2bf((v.w - mu) * rs * gv.w + bv.w);
    ((ushort4*)y)[(size_t)row * 256 + t] = o4;
  } else if (bid < 7168) {
    // transpose tile 32x32, c_attn_w R=1024, C=3072
    __shared__ float tile[32][33];
    int bb = bid - 4096;
    int bx = bb % 96, by = bb / 96;
    int tx = t & 31, ty = t >> 5;   // 32 x 8
    int x2 = bx * 32 + tx;
    int y0 = by * 32;
    #pragma unroll
    for (int j = 0; j < 32; j += 8)
      tile[ty + j][tx] = c_attn_w[(size_t)(y0 + ty + j) * 3072 + x2];
    __syncthreads();
    int ox  = by * 32 + tx;
    int oy0 = bx * 32;
    #pragma unroll
    for (int j = 0; j < 32; j += 8)
      wqkv[(size_t)(oy0 + ty + j) * 1024 + ox] = f2bf(tile[tx][ty + j]);
  } else if (bid < 9216) {
    bool iswp = bid < 8192;
    int bb = bid - (iswp ? 7168 : 8192);
    const float* in = iswp ? c_proj_w : to_out_w;
    unsigned short* out = iswp ? wpbf : wout;
    int i = (bb * 256 + t) * 4;
    float4 v = *(const float4*)(in + i);
    ushort4 o;
    o.x = f2bf(v.x); o.y = f2bf(v.y); o.z = f2bf(v.z); o.w = f2bf(v.w);
    *(ushort4*)(out + i) = o;
  } else {
    int n = (bid - 9216) * 4 + (t >> 6);
    int lane = t & 63;
    const float4* w = (const float4*)(to_out_w + (size_t)n * DIMM);
    const float4* b4 = (const float4*)c_proj_b;
    float s = 0.0f;
    #pragma unroll
    for (int k = 0; k < 4; k++) {
      float4 wv = w[lane + k * 64], bv = b4[lane + k * 64];
      s += wv.x * bv.x + wv.y * bv.y + wv.z * bv.z + wv.w * bv.w;
    }
    #pragma unroll
    for (int o = 1; o < 64; o <<= 1) s += __shfl_xor(s, o);
    if (lane == 0) bc[n] = s;
  }
}

// ---------------------------------------------------------------------------
// NT GEMM body: C[M,N] = A[M,K] * Bt[N,K]^T (+bias). 128x128 tile, BK=64,
// 4 waves. XOR-swizzled LDS (chunk ^= row&7) to kill bank conflicts.
// EPI 0: qkv epilogue: q/k scatter [B,H,N,DH] with fused L2-norm (q*8, k);
//        v-blocks transpose through LDS and write vt [B,H,DH,N] directly.
// EPI 2: fp32 out [M,N] + bias
// EPI 3: bf16 out [M,N], no bias
template <int EPI>
__device__ __forceinline__ void gemm_body(
    const unsigned short* __restrict__ A, const unsigned short* __restrict__ Bt,
    const float* __restrict__ bias,
    unsigned short* __restrict__ obf, float* __restrict__ of32,
    unsigned short* __restrict__ q_std, unsigned short* __restrict__ k_std,
    unsigned short* __restrict__ vt_out,
    int M, int N, int K, int bn, int bm,
    unsigned short* smem) {
  unsigned short* sA = smem;
  unsigned short* sB = smem + 128 * 64;
  int t = threadIdx.x;
  int lane = t & 63, wv = t >> 6;
  int wm = (wv >> 1) * 64, wn = (wv & 1) * 64;
  int l16 = lane & 15, quad = lane >> 4;

  const unsigned short* Ab = A + (size_t)(bm * 128) * K;
  const unsigned short* Bb2 = Bt + (size_t)(bn * 128) * K;
  int srow = t >> 3;                     // 0..31
  int gch = (t & 7) ^ (srow & 7);        // swizzled global chunk for this lane

  f32x4 acc[4][4] = {};

  for (int kt = 0; kt < K; kt += 64) {
    __syncthreads();
    #pragma unroll
    for (int i = 0; i < 4; i++) {
      GLDS16(Ab  + (size_t)(srow + 32 * i) * K + kt + gch * 8, sA + (size_t)(t + 256 * i) * 8);
      GLDS16(Bb2 + (size_t)(srow + 32 * i) * K + kt + gch * 8, sB + (size_t)(t + 256 * i) * 8);
    }
    __syncthreads();
    #pragma unroll
    for (int kk = 0; kk < 2; kk++) {
      int slot = (kk * 4 + quad) ^ (l16 & 7);
      bf16x8 af[4], bfr[4];
      #pragma unroll
      for (int i = 0; i < 4; i++)
        af[i] = *(const bf16x8*)(sA + (size_t)(wm + i * 16 + l16) * 64 + slot * 8);
      #pragma unroll
      for (int j = 0; j < 4; j++)
        bfr[j] = *(const bf16x8*)(sB + (size_t)(wn + j * 16 + l16) * 64 + slot * 8);
      #pragma unroll
      for (int i = 0; i < 4; i++)
        #pragma unroll
        for (int j = 0; j < 4; j++)
          acc[i][j] = __builtin_amdgcn_mfma_f32_16x16x32_bf16(af[i], bfr[j], acc[i][j], 0, 0, 0);
    }
  }

  // epilogue: D row = quad*4+reg, col = l16
  float bvals[4];
  #pragma unroll
  for (int j = 0; j < 4; j++)
    bvals[j] = (EPI == 3) ? 0.0f : bias[bn * 128 + wn + j * 16 + l16];

  if (EPI == 0) {
    int which = bn >> 3;                 // 0=q 1=k 2=v  (block-uniform)
    if (which < 2) {
      #pragma unroll
      for (int i = 0; i < 4; i++) {
        #pragma unroll
        for (int r = 0; r < 4; r++) {
          int m = bm * 128 + wm + i * 16 + quad * 4 + r;
          float vals[4];
          float ss = 0.0f;
          #pragma unroll
          for (int j = 0; j < 4; j++) {
            vals[j] = acc[i][j][r] + bvals[j];
            ss += vals[j] * vals[j];
          }
          ss += __shfl_xor(ss, 1); ss += __shfl_xor(ss, 2);
          ss += __shfl_xor(ss, 4); ss += __shfl_xor(ss, 8);
          float scale = ((which == 0) ? 8.0f : 1.0f) / fmaxf(sqrtf(ss), 1e-12f);
          int bi = m >> 11, ns = m & 2047;
          unsigned short* dst = (which == 0) ? q_std : k_std;
          #pragma unroll
          for (int j = 0; j < 4; j++) {
            int n = bn * 128 + wn + j * 16 + l16;
            int nn2 = n & 1023;
            int h = nn2 >> 6, d = nn2 & 63;
            dst[((size_t)((bi * Hh + h) * Nn + ns)) * DHh + d] = f2bf(vals[j] * scale);
          }
        }
      }
    } else {
      // v-block: transpose tile through LDS (32 KB, reuses sA/sB), write
      // vt[bh][d][n_seq] with coalesced-ish 8B stores. Swizzle at 4-short
      // granularity: chunk c (m_local>>2), c' = c ^ (n_local & 31).
      __syncthreads();                   // all waves done with sA/sB reads
      #pragma unroll
      for (int i = 0; i < 4; i++) {
        int mchunk = (wm + i * 16) / 4 + quad;   // 0..31
        #pragma unroll
        for (int j = 0; j < 4; j++) {
          int n_local = wn + j * 16 + l16;
          int sw = mchunk ^ (n_local & 31);
          ushort4 pack;
          pack.x = f2bf(acc[i][j][0] + bvals[j]);
          pack.y = f2bf(acc[i][j][1] + bvals[j]);
          pack.z = f2bf(acc[i][j][2] + bvals[j]);
          pack.w = f2bf(acc[i][j][3] + bvals[j]);
          *(ushort4*)(smem + (size_t)n_local * 128 + sw * 4) = pack;
        }
      }
      __syncthreads();
      // thread t: row d = t>>1 (n_local), m-half = t&1 (64 m-values, 16 chunks)
      int drow = t >> 1, mh = t & 1;
      int h = (bn - 16) * 2 + (drow >> 6);
      int d = drow & 63;
      int bi = bm >> 4;
      int ns0 = (bm * 128) & 2047;
      unsigned short* dst = vt_out + ((size_t)(bi * Hh + h) * DHh + d) * Nn + ns0 + mh * 64;
      #pragma unroll
      for (int cc = 0; cc < 16; cc++) {
        int c0 = mh * 16 + cc;
        int s0 = c0 ^ (drow & 31);
        *(ushort4*)(dst + cc * 4) = *(const ushort4*)(smem + (size_t)drow * 128 + s0 * 4);
      }
    }
  } else {
    #pragma unroll
    for (int i = 0; i < 4; i++) {
      #pragma unroll
      for (int j = 0; j < 4; j++) {
        int n = bn * 128 + wn + j * 16 + l16;
        #pragma unroll
        for (int r = 0; r < 4; r++) {
          int m = bm * 128 + wm + i * 16 + quad * 4 + r;
          float val = acc[i][j][r] + bvals[j];
          if (EPI == 2) of32[(size_t)m * N + n] = val;
          else          obf[(size_t)m * N + n] = f2bf(val);
        }
      }
    }
  }
}

// Fused launch: qkv GEMM (bn<24, grid 24x32) + wcomb GEMM (bn in {24,25},
// remapped to the 8x8 tile grid of wcomb[n][j] = sum_c Wo[n][c]*Wp[j][c]).
__global__ __launch_bounds__(256) void gemm_qkv_wcomb(
    const unsigned short* __restrict__ y, const unsigned short* __restrict__ wqkv,
    const float* __restrict__ c_attn_b,
    unsigned short* __restrict__ q_std, unsigned short* __restrict__ k_std,
    unsigned short* __restrict__ vt_out,
    const unsigned short* __restrict__ wout, const unsigned short* __restrict__ wpbf,
    unsigned short* __restrict__ wcomb) {
  __shared__ unsigned short smem[128 * 64 * 2];
  int bn = blockIdx.x, bm = blockIdx.y;
  if (bn < 24) {
    gemm_body<0>(y, wqkv, c_attn_b, nullptr, nullptr, q_std, k_std, vt_out,
                 MROWS, 3 * DIMM, DIMM, bn, bm, smem);
  } else {
    int idx = (bn - 24) * 32 + bm;       // 0..63
    gemm_body<3>(wout, wpbf, nullptr, wcomb, nullptr, nullptr, nullptr, nullptr,
                 DIMM, DIMM, DIMM, idx & 7, idx >> 3, smem);
  }
}

// Standalone final GEMM (fp32 out + bias)
__global__ __launch_bounds__(256) void gemm_final(
    const unsigned short* __restrict__ A, const unsigned short* __restrict__ Bt,
    const float* __restrict__ bias, float* __restrict__ of32) {
  __shared__ unsigned short smem[128 * 64 * 2];
  gemm_body<2>(A, Bt, bias, nullptr, of32, nullptr, nullptr, nullptr,
               MROWS, DIMM, DIMM, blockIdx.x, blockIdx.y, smem);
}

// ---------------------------------------------------------------------------
// Causal cosine-sim attention (R5 structure — best measured), register-
// resident P, split-j within the block: 8 waves (512 thr). Waves 0-3 (half 0)
// process j-tiles [0, nh); waves 4-7 (half 1) process [nh, 2nh), nh = qb+1.
// Equal trip counts -> uniform barriers, halved serial critical path. Each
// half stages K/V into its own LDS buffer via global_load_lds. Epilogue
// merges (num, den) of the two halves through LDS.
//   S^T = K·Q^T via mfma(A=K, B=Q);  P^T exp'd in-register = B-operand of
//   16x16x16 MFMA;  O^T[d][m] += V^T[d][j]·P^T[j][m]
// NOTE (R7 lesson): do NOT add cross-iteration register prefetch here — at
// __launch_bounds__(512,4) the VGPR budget has no headroom and the staging
// registers spill to scratch (HBM), costing ~10 µs (WRITE_SIZE 10->22 MB).
// Grid: 512 blocks, paired ordering (heavy+light co-resident).
__global__ __launch_bounds__(512, 4) void attn_kernel(
    const unsigned short* __restrict__ qn, const unsigned short* __restrict__ kn,
    const unsigned short* __restrict__ vt, unsigned short* __restrict__ o_flat) {
  __shared__ float smemf[8704];   // 34816 B: 2x(K8KB+V8KB) tiles / merge scratch
  int t = threadIdx.x, lane = t & 63, wv = t >> 6;
  int half = wv >> 2, strip = wv & 3;
  int l16 = lane & 15, quad = lane >> 4;
  int id = blockIdx.x;
  int qb = (id < 256) ? (15 - (id >> 5)) : ((id - 256) >> 5);  // pair heavy+light
  int bh = id & 31;
  int m0 = qb * 128 + strip * 32;               // wave's first q row (seq index)
  const unsigned short* qbase = qn + (size_t)bh * Nn * DHh;
  const unsigned short* kbase = kn + (size_t)bh * Nn * DHh;
  const unsigned short* vbase = vt + (size_t)bh * DHh * Nn;

  unsigned short* myK = (unsigned short*)((char*)smemf + half * 16384);
  unsigned short* myV = (unsigned short*)((char*)smemf + half * 16384 + 8192);

  // Q fragments (q pre-scaled by 8); same lane layout serves as MFMA B-operand
  bf16x8 aq[2][2];
  #pragma unroll
  for (int i2 = 0; i2 < 2; i2++)
    #pragma unroll
    for (int kk = 0; kk < 2; kk++)
      aq[i2][kk] = *(const bf16x8*)(qbase + (size_t)(m0 + i2 * 16 + l16) * DHh + kk * 32 + quad * 8);

  f32x4 accOT[4][2] = {};       // [dt][i2]: O^T, row=d=quad*4+r, col=m=l16
  float den[2] = {};            // per-lane partial: m = i2*16+l16 (quad-partial)

  int tl = t & 255;                      // thread-in-halfgroup
  int srow = tl >> 3;                    // 0..31
  int gch = (tl & 7) ^ (srow & 7);       // swizzled chunk
  int nh = qb + 1;                       // tiles per half
  int kt0 = half * nh;

  for (int kt = 0; kt < nh; kt++) {
    int j0 = (kt0 + kt) * 64;
    __syncthreads();
    GLDS16(kbase + (size_t)(j0 + srow)      * DHh + gch * 8, myK + (size_t)tl * 8);
    GLDS16(kbase + (size_t)(j0 + srow + 32) * DHh + gch * 8, myK + (size_t)(tl + 256) * 8);
    GLDS16(vbase + (size_t)srow        * Nn + j0 + gch * 8, myV + (size_t)tl * 8);
    GLDS16(vbase + (size_t)(srow + 32) * Nn + j0 + gch * 8, myV + (size_t)(tl + 256) * 8);
    __syncthreads();

    if (j0 > m0 + 31) continue;          // fully masked for this wave (uniform)

    // S^T = K·Q^T : sc[jt][i2], row=j_local=quad*4+r, col=m_local=l16
    f32x4 sc[4][2] = {};
    #pragma unroll
    for (int kk = 0; kk < 2; kk++) {
      int slot = (kk * 4 + quad) ^ (l16 & 7);
      #pragma unroll
      for (int jt = 0; jt < 4; jt++) {
        bf16x8 ak = *(const bf16x8*)(myK + (size_t)(jt * 16 + l16) * 64 + slot * 8);
        #pragma unroll
        for (int i2 = 0; i2 < 2; i2++)
          sc[jt][i2] = __builtin_amdgcn_mfma_f32_16x16x32_bf16(ak, aq[i2][kk], sc[jt][i2], 0, 0, 0);
      }
    }

    // exp(s-8) in-register; P^T bf16 is directly the 16x16x16 B-operand
    bool fullTile = (j0 + 63) <= m0;     // wave-uniform
    s16x4 pf[4][2];
    #pragma unroll
    for (int jt = 0; jt < 4; jt++) {
      #pragma unroll
      for (int i2 = 0; i2 < 2; i2++) {
        int m = m0 + i2 * 16 + l16;
        #pragma unroll
        for (int r = 0; r < 4; r++) {
          int j = j0 + jt * 16 + quad * 4 + r;
          float p;
          if (fullTile) p = __expf(sc[jt][i2][r] - 8.0f);
          else          p = (j <= m) ? __expf(sc[jt][i2][r] - 8.0f) : 0.0f;
          den[i2] += p;
          pf[jt][i2][r] = (short)f2bf_fast(p);
        }
      }
    }

    // O^T += V^T · P^T   (A = V^T frag from LDS, 4 bf16/lane: [d=l16][j=quad*4+i])
    #pragma unroll
    for (int jt = 0; jt < 4; jt++) {
      #pragma unroll
      for (int dt = 0; dt < 4; dt++) {
        int row = dt * 16 + l16;
        int ch = (jt * 2 + (quad >> 1)) ^ (l16 & 7);
        s16x4 av = *(const s16x4*)(myV + (size_t)row * 64 + ch * 8 + (quad & 1) * 4);
        #pragma unroll
        for (int i2 = 0; i2 < 2; i2++)
          accOT[dt][i2] = __builtin_amdgcn_mfma_f32_16x16x16bf16_1k(av, pf[jt][i2], accOT[dt][i2], 0, 0, 0);
      }
    }
  }

  // intra-wave den reduction across quads (j-direction lives on lane>>4)
  #pragma unroll
  for (int i2 = 0; i2 < 2; i2++) {
    float d = den[i2];
    d += __shfl_xor(d, 16); d += __shfl_xor(d, 32);
    den[i2] = d;
  }

  // merge halves through LDS (reuse tile buffers; all loop reads done)
  __syncthreads();
  float* scr = smemf + strip * 2176;     // 2048 acc + 128 den per strip
  if (half == 1) {
    #pragma unroll
    for (int dt = 0; dt < 4; dt++)
      #pragma unroll
      for (int i2 = 0; i2 < 2; i2++)
        *(f32x4*)(scr + ((size_t)(dt * 2 + i2) * 64 + lane) * 4) = accOT[dt][i2];
    scr[2048 + lane] = den[0];
    scr[2048 + 64 + lane] = den[1];
  }
  __syncthreads();
  if (half == 0) {
    float dinv[2];
    dinv[0] = 1.0f / (den[0] + scr[2048 + lane]);
    dinv[1] = 1.0f / (den[1] + scr[2048 + 64 + lane]);
    int bi = bh >> 4, h = bh & 15;
    #pragma unroll
    for (int i2 = 0; i2 < 2; i2++) {
      #pragma unroll
      for (int dt = 0; dt < 4; dt++) {
        f32x4 o = accOT[dt][i2] + *(const f32x4*)(scr + ((size_t)(dt * 2 + i2) * 64 + lane) * 4);
        ushort4 o4;
        o4.x = f2bf(o[0] * dinv[i2]);
        o4.y = f2bf(o[1] * dinv[i2]);
        o4.z = f2bf(o[2] * dinv[i2]);
        o4.w = f2bf(o[3] * dinv[i2]);
        int ns = m0 + i2 * 16 + l16;
        int d0 = dt * 16 + quad * 4;
        *(ushort4*)(o_flat + ((size_t)(bi * Nn + ns)) * DIMM + h * DHh + d0) = o4;
      }
    }
  }
}

// ---------------------------------------------------------------------------
extern "C" void kernel_launch(void* const* d_in, const int* in_sizes, int n_in,
                              void* d_out, int out_size, void* d_ws, size_t ws_size,
                              hipStream_t stream) {
  const float* x        = (const float*)d_in[0];
  const float* g        = (const float*)d_in[1];
  const float* b        = (const float*)d_in[2];
  const float* c_attn_w = (const float*)d_in[3];
  const float* c_attn_b = (const float*)d_in[4];
  const float* c_proj_w = (const float*)d_in[5];
  const float* c_proj_b = (const float*)d_in[6];
  const float* to_out_w = (const float*)d_in[7];
  float* out = (float*)d_out;

  char* p = (char*)d_ws;
  unsigned short* y     = (unsigned short*)(p + ((size_t)0  << 20)); // 8 MB (also o_flat)
  unsigned short* qbuf  = (unsigned short*)(p + ((size_t)8  << 20)); // 8 MB
  unsigned short* kbuf  = (unsigned short*)(p + ((size_t)16 << 20)); // 8 MB
  unsigned short* vtb   = (unsigned short*)(p + ((size_t)24 << 20)); // 8 MB (V^T, written by qkv epilogue)
  unsigned short* wpbf  = (unsigned short*)(p + ((size_t)32 << 20)); // 2 MB
  unsigned short* wout  = (unsigned short*)(p + ((size_t)34 << 20)); // 2 MB
  unsigned short* wqkv  = (unsigned short*)(p + ((size_t)40 << 20)); // 6 MB
  unsigned short* wcomb = (unsigned short*)(p + ((size_t)46 << 20)); // 2 MB
  float*          bc    = (float*)        (p + ((size_t)48 << 20)); // 4 KB

  // 1. fused prep: LayerNorm -> y, transpose c_attn_w, convert wp/wout, bias
  prep_kernel<<<9472, 256, 0, stream>>>(x, g, b, c_attn_w, c_proj_w, to_out_w,
                                        c_proj_b, y, wqkv, wpbf, wout, bc);
  // 2. qkv GEMM (+fused l2norm, +fused V-transpose) with wcomb GEMM riding
  gemm_qkv_wcomb<<<dim3(26, MROWS / 128), 256, 0, stream>>>(
      y, wqkv, c_attn_b, qbuf, kbuf, vtb, wout, wpbf, wcomb);
  // 3. attention -> o_flat (reuses y)
  attn_kernel<<<512, 512, 0, stream>>>(qbuf, kbuf, vtb, y);
  // 4. fused (c_proj ∘ to_out): out = o_flat @ wcomb^T + bc  (fp32)
  gemm_final<<<dim3(DIMM / 128, MROWS / 128), 256, 0, stream>>>(y, wcomb, bc, out);
}